// Round 10
// baseline (184.699 us; speedup 1.0000x reference)
//
#include <hip/hip_runtime.h>
#include <math.h>

#define CC 256
#define KK 8
#define MM 6
#define SS 3
#define NVOX 12000
#define VB 16
#define NBLK (NVOX / VB)

typedef __attribute__((ext_vector_type(8))) short bf16x8;
typedef __attribute__((ext_vector_type(4))) float f32x4;
typedef __attribute__((ext_vector_type(4))) float fvec4;

// ---- ws layout (bytes) ----
#define OFF_QK3PK  0u           // uint4 [48ng][8kb][64lane]
#define OFF_WBIGPK 393216u      // uint4 [16ng][24kb][64lane]
#define OFF_WVOCPK 786432u      // uint4 [16ng][8kb][64lane]
#define OFF_BQK    917504u      // f32 [3][256]
#define OFF_BBIG   920576u      // f32 [256]
#define OFF_BVOC   921600u      // f32 [256]
#define WS_NEED    922624u

__device__ __forceinline__ float wred(float p) {
  #pragma unroll
  for (int off = 32; off; off >>= 1) p += __shfl_xor(p, off, 64);
  return p;
}
__device__ __forceinline__ uint f2bf(float x) {  // RNE to bf16 bits
  const uint u = __float_as_uint(x);
  return (u + 0x7fffu + ((u >> 16) & 1u)) >> 16;
}
__device__ __forceinline__ uint bfpack(float a, float b) {
  return (f2bf(b) << 16) | f2bf(a);
}
__device__ __forceinline__ float bflo(uint w) { return __uint_as_float(w << 16); }
__device__ __forceinline__ float bfhi(uint w) { return __uint_as_float(w & 0xffff0000u); }

__device__ __forceinline__ f32x4 mfma16(bf16x8 a, bf16x8 b, f32x4 c) {
  return __builtin_amdgcn_mfma_f32_16x16x32_bf16(a, b, c, 0, 0, 0);
}

// ---------------- single prep kernel: all folds, packed outputs ----------------
__global__ __launch_bounds__(256) void prep_all(
    const float* __restrict__ Wq_t, const float* __restrict__ Wq_c,
    const float* __restrict__ Wk_t, const float* __restrict__ Wk_c,
    const float* __restrict__ Wv_t, const float* __restrict__ Wv_c,
    const float* __restrict__ Wo_t, const float* __restrict__ Wo_c,
    const float* __restrict__ bq_t, const float* __restrict__ bq_c,
    const float* __restrict__ bv_t, const float* __restrict__ bv_c,
    const float* __restrict__ bo_t, const float* __restrict__ bo_c,
    uint4* __restrict__ qk3pk, uint4* __restrict__ wbigpk,
    uint4* __restrict__ wvocpk,
    float* __restrict__ bqk, float* __restrict__ bbig,
    float* __restrict__ bvoc) {
  const int b = blockIdx.x, t = threadIdx.x;
  __shared__ float xl[8][256];
  if (b < 96) {
    const int u = b >> 5, c0 = (b & 31) * 8;
    const float* Wq = Wq_t + u * 65536;
    const float* Wk = Wk_t + u * 65536;
    #pragma unroll
    for (int i = 0; i < 8; ++i) xl[i][t] = Wq[(c0 + i) * 256 + t];
    __syncthreads();
    float acc[8] = {0.f, 0.f, 0.f, 0.f, 0.f, 0.f, 0.f, 0.f};
    const float4* wr = (const float4*)(Wk + t * 256);
    #pragma unroll 4
    for (int d4 = 0; d4 < 64; ++d4) {
      const float4 wv = wr[d4];
      #pragma unroll
      for (int j = 0; j < 8; ++j)
        acc[j] += xl[j][d4 * 4] * wv.x + xl[j][d4 * 4 + 1] * wv.y +
                  xl[j][d4 * 4 + 2] * wv.z + xl[j][d4 * 4 + 3] * wv.w;
    }
    const int lane = (((c0 >> 3) & 3) << 4) | (t & 15);
    uint4 o;
    o.x = bfpack(acc[0], acc[1]); o.y = bfpack(acc[2], acc[3]);
    o.z = bfpack(acc[4], acc[5]); o.w = bfpack(acc[6], acc[7]);
    qk3pk[((u * 16 + (t >> 4)) * 8 + (c0 >> 5)) * 64 + lane] = o;
  } else if (b < 192) {
    const int v = (b - 96) >> 5, bi = (b - 96) & 31;
    const int c0 = bi * 8, row0 = v * 256 + c0;
    const float* Wv = Wv_t + v * 65536;
    const float* Wo = Wo_t + v * 65536;
    #pragma unroll
    for (int i = 0; i < 8; ++i) xl[i][t] = Wv[(c0 + i) * 256 + t];
    __syncthreads();
    float a1[8] = {0.f, 0.f, 0.f, 0.f, 0.f, 0.f, 0.f, 0.f};
    #pragma unroll 4
    for (int d = 0; d < 256; ++d) {
      const float w = Wo[d * 256 + t];
      #pragma unroll
      for (int j = 0; j < 8; ++j) a1[j] += xl[j][d] * w;
    }
    __syncthreads();
    #pragma unroll
    for (int j = 0; j < 8; ++j) xl[j][t] = a1[j];
    __syncthreads();
    float a2[8] = {0.f, 0.f, 0.f, 0.f, 0.f, 0.f, 0.f, 0.f};
    #pragma unroll 4
    for (int d = 0; d < 256; ++d) {
      const float w = Wq_c[d * 256 + t];
      #pragma unroll
      for (int j = 0; j < 8; ++j) a2[j] += xl[j][d] * w;
    }
    __syncthreads();
    #pragma unroll
    for (int j = 0; j < 8; ++j) xl[j][t] = a2[j];
    __syncthreads();
    float a3[8] = {0.f, 0.f, 0.f, 0.f, 0.f, 0.f, 0.f, 0.f};
    const float4* wr = (const float4*)(Wk_c + t * 256);
    #pragma unroll 4
    for (int d4 = 0; d4 < 64; ++d4) {
      const float4 wv = wr[d4];
      #pragma unroll
      for (int j = 0; j < 8; ++j)
        a3[j] += xl[j][d4 * 4] * wv.x + xl[j][d4 * 4 + 1] * wv.y +
                 xl[j][d4 * 4 + 2] * wv.z + xl[j][d4 * 4 + 3] * wv.w;
    }
    const int lane = (((row0 >> 3) & 3) << 4) | (t & 15);
    uint4 o;
    o.x = bfpack(a3[0], a3[1]); o.y = bfpack(a3[2], a3[3]);
    o.z = bfpack(a3[4], a3[5]); o.w = bfpack(a3[6], a3[7]);
    wbigpk[((t >> 4) * 24 + (row0 >> 5)) * 64 + lane] = o;
  } else if (b < 224) {
    const int c0 = (b - 192) * 8;
    #pragma unroll
    for (int i = 0; i < 8; ++i) xl[i][t] = Wv_c[(c0 + i) * 256 + t];
    __syncthreads();
    float acc[8] = {0.f, 0.f, 0.f, 0.f, 0.f, 0.f, 0.f, 0.f};
    #pragma unroll 4
    for (int d = 0; d < 256; ++d) {
      const float w = Wo_c[d * 256 + t];
      #pragma unroll
      for (int j = 0; j < 8; ++j) acc[j] += xl[j][d] * w;
    }
    const int lane = (((c0 >> 3) & 3) << 4) | (t & 15);
    uint4 o;
    o.x = bfpack(acc[0], acc[1]); o.y = bfpack(acc[2], acc[3]);
    o.z = bfpack(acc[4], acc[5]); o.w = bfpack(acc[6], acc[7]);
    wvocpk[((t >> 4) * 8 + (c0 >> 5)) * 64 + lane] = o;
  } else if (b < 227) {
    const int u = b - 224;
    xl[0][t] = bq_t[u * 256 + t];
    __syncthreads();
    const float4* wr = (const float4*)(Wk_t + u * 65536 + t * 256);
    float a = 0.f;
    #pragma unroll 4
    for (int d4 = 0; d4 < 64; ++d4) {
      const float4 wv = wr[d4];
      a += xl[0][d4 * 4] * wv.x + xl[0][d4 * 4 + 1] * wv.y +
           xl[0][d4 * 4 + 2] * wv.z + xl[0][d4 * 4 + 3] * wv.w;
    }
    bqk[u * 256 + t] = a;
  } else {
    xl[0][t] = bv_t[t]; xl[1][t] = bv_t[256 + t];
    xl[2][t] = bv_t[512 + t]; xl[3][t] = bv_c[t];
    __syncthreads();
    float bvs = bo_t[t] + bo_t[256 + t] + bo_t[512 + t];
    float bvc = bo_c[t];
    #pragma unroll 2
    for (int d = 0; d < 256; ++d) {
      bvs += xl[0][d] * Wo_t[d * 256 + t] +
             xl[1][d] * Wo_t[65536 + d * 256 + t] +
             xl[2][d] * Wo_t[131072 + d * 256 + t];
      bvc += xl[3][d] * Wo_c[d * 256 + t];
    }
    bvoc[t] = bvc;
    __syncthreads();
    xl[4][t] = bvs;
    __syncthreads();
    float y = bq_c[t];
    #pragma unroll 4
    for (int d = 0; d < 256; ++d) y += xl[4][d] * Wq_c[d * 256 + t];
    __syncthreads();
    xl[5][t] = y;
    __syncthreads();
    const float4* wr = (const float4*)(Wk_c + t * 256);
    float bb = 0.f;
    #pragma unroll 4
    for (int d4 = 0; d4 < 64; ++d4) {
      const float4 wv = wr[d4];
      bb += xl[5][d4 * 4] * wv.x + xl[5][d4 * 4 + 1] * wv.y +
            xl[5][d4 * 4 + 2] * wv.z + xl[5][d4 * 4 + 3] * wv.w;
    }
    bbig[t] = bb;
  }
}

// ---------------- mega kernel: R8 structure + register prefetch pipeline ----------------
// shA: U bf16[16][776] (ph1->ph2) / Uc bf16[16][264] (ph3->ph4) / Ost f32[16][260]@8448 (ph5)
// shB: qb bf16[16][264] (ph1) / wagg bf16[16][776] (ph2->ph3) / cagg bf16[16][264] (ph4->ph5)
__global__ __launch_bounds__(512, 4) void stftr_mega(
    const float* __restrict__ ptsf, const float* __restrict__ ptspe,
    const float* __restrict__ knnf, const float* __restrict__ knnpe,
    const float* __restrict__ sfeat, const int* __restrict__ maskp,
    const bf16x8* __restrict__ qk3pk, const bf16x8* __restrict__ wbigpk,
    const bf16x8* __restrict__ wvocpk,
    const float* __restrict__ bqk, const float* __restrict__ bbig,
    const float* __restrict__ bvoc,
    float* __restrict__ out) {
  __shared__ char shA[25088];
  __shared__ char shB[24832];
  __shared__ int mlds[VB * MM];
  __shared__ int vlds[VB];
  const int t = threadIdx.x, lane = t & 63, w = t >> 6;
  const int g0 = blockIdx.x * VB;
  const fvec4* kfp = (const fvec4*)knnf;
  const fvec4* kpp = (const fvec4*)knnpe;
  const fvec4* sfp = (const fvec4*)sfeat;

  // prologue prefetch: task-0 kv rows for this wave (independent of all phases)
  fvec4 pkf[KK], pkp[KK];
  {
    const int tid0 = w * 6;
    const int s0 = tid0 >> 4, j0 = tid0 & 15;
    const size_t rb0 = ((size_t)(s0 * NVOX + g0 + j0)) * 512 + lane;
    #pragma unroll
    for (int r = 0; r < KK; ++r) {
      pkf[r] = __builtin_nontemporal_load(&kfp[rb0 + r * 64]);
      pkp[r] = __builtin_nontemporal_load(&kpp[rb0 + r * 64]);
    }
  }

  // phase 1a: stage qb = bf16(ptsf+ptspe) into shB ; preload mask
  {
    uint* qb_u = (uint*)shB;
    const fvec4* a4 = (const fvec4*)(ptsf + (size_t)g0 * CC);
    const fvec4* b4 = (const fvec4*)(ptspe + (size_t)g0 * CC);
    #pragma unroll
    for (int it = 0; it < 2; ++it) {
      const int idx = it * 512 + t;
      const int row = idx >> 6, c4 = idx & 63;
      const fvec4 va = __builtin_nontemporal_load(&a4[idx]);
      const fvec4 vb = __builtin_nontemporal_load(&b4[idx]);
      qb_u[row * 132 + c4 * 2]     = bfpack(va.x + vb.x, va.y + vb.y);
      qb_u[row * 132 + c4 * 2 + 1] = bfpack(va.z + vb.z, va.w + vb.w);
    }
    if (t < VB * MM) mlds[t] = maskp[g0 * MM + t];
  }
  __syncthreads();
  // phase 1b: U = qb @ Wqk3 + bqk  (N=768) -> shA
  {
    f32x4 acc[6];
    #pragma unroll
    for (int nb = 0; nb < 6; ++nb) acc[nb] = (f32x4){0.f, 0.f, 0.f, 0.f};
    const char* qbase = shB + (lane & 15) * 528 + (lane >> 4) * 16;
    #pragma unroll
    for (int kb = 0; kb < 8; ++kb) {
      const bf16x8 a = *(const bf16x8*)(qbase + kb * 64);
      #pragma unroll
      for (int nb = 0; nb < 6; ++nb) {
        const bf16x8 bb = qk3pk[((w * 6 + nb) * 8 + kb) * 64 + lane];
        acc[nb] = mfma16(a, bb, acc[nb]);
      }
    }
    ushort* us = (ushort*)shA;
    #pragma unroll
    for (int nb = 0; nb < 6; ++nb) {
      const int n = (w * 6 + nb) * 16 + (lane & 15);
      const float bias = bqk[n];
      #pragma unroll
      for (int r = 0; r < 4; ++r) {
        const int row = (lane >> 4) * 4 + r;
        us[row * 776 + n] = (ushort)f2bf(acc[nb][r] + bias);
      }
    }
  }
  __syncthreads();
  // phase 2: 48 temporal score tasks; wave w handles 6, software-pipelined
  fvec4 psf[2][MM];   // sfeat prefetch issued at q==5
  {
    const uint* Au = (const uint*)shA;
    uint* Bu = (uint*)shB;
    #pragma unroll
    for (int q = 0; q < 6; ++q) {
      const int tid = w * 6 + q;
      const int s = tid >> 4, j = tid & 15;
      // consume pending buffers
      fvec4 sm[KK];
      #pragma unroll
      for (int r = 0; r < KK; ++r) sm[r] = pkf[r] + pkp[r];
      // issue next loads immediately (ride under this task's compute)
      if (q < 5) {
        const int tid1 = tid + 1;
        const int s1 = tid1 >> 4, j1 = tid1 & 15;
        const size_t rb1 = ((size_t)(s1 * NVOX + g0 + j1)) * 512 + lane;
        #pragma unroll
        for (int r = 0; r < KK; ++r) {
          pkf[r] = __builtin_nontemporal_load(&kfp[rb1 + r * 64]);
          pkp[r] = __builtin_nontemporal_load(&kpp[rb1 + r * 64]);
        }
      } else {
        // last task: issue ph4 sfeat prefetch instead (independent of Uc)
        #pragma unroll
        for (int jj = 0; jj < 2; ++jj) {
          const int g = g0 + w * 2 + jj;
          const size_t sb = (size_t)g * (MM * 64) + lane;
          #pragma unroll
          for (int m = 0; m < MM; ++m)
            psf[jj][m] = __builtin_nontemporal_load(&sfp[sb + m * 64]);
        }
      }
      // scores -> softmax -> aggregate
      const uint ua = Au[j * 388 + s * 128 + lane * 2];
      const uint ub = Au[j * 388 + s * 128 + lane * 2 + 1];
      const float u0 = bflo(ua), u1 = bfhi(ua), u2 = bflo(ub), u3 = bfhi(ub);
      float sc[KK];
      #pragma unroll
      for (int r = 0; r < KK; ++r) {
        float p = sm[r].x * u0 + sm[r].y * u1 + sm[r].z * u2 + sm[r].w * u3;
        sc[r] = wred(p);
      }
      float mx = sc[0];
      #pragma unroll
      for (int r = 1; r < KK; ++r) mx = fmaxf(mx, sc[r]);
      float e[KK], sum = 0.f;
      #pragma unroll
      for (int r = 0; r < KK; ++r) { e[r] = __expf((sc[r] - mx) * 0.0625f); sum += e[r]; }
      const float inv = 1.f / sum;
      fvec4 acc = (fvec4){0.f, 0.f, 0.f, 0.f};
      #pragma unroll
      for (int r = 0; r < KK; ++r) acc += (e[r] * inv) * sm[r];
      Bu[j * 388 + s * 128 + lane * 2]     = bfpack(acc.x, acc.y);
      Bu[j * 388 + s * 128 + lane * 2 + 1] = bfpack(acc.z, acc.w);
    }
  }
  __syncthreads();
  // phase 3: Uc = wagg_cat @ Wbig + bbig  (K=768, N=256) -> shA
  {
    f32x4 acc[2];
    acc[0] = (f32x4){0.f, 0.f, 0.f, 0.f};
    acc[1] = (f32x4){0.f, 0.f, 0.f, 0.f};
    const char* abase = shB + (lane & 15) * 1552 + (lane >> 4) * 16;
    #pragma unroll 4
    for (int kb = 0; kb < 24; ++kb) {
      const bf16x8 a = *(const bf16x8*)(abase + kb * 64);
      #pragma unroll
      for (int nb = 0; nb < 2; ++nb) {
        const bf16x8 bb = wbigpk[((w * 2 + nb) * 24 + kb) * 64 + lane];
        acc[nb] = mfma16(a, bb, acc[nb]);
      }
    }
    ushort* ust = (ushort*)shA;
    #pragma unroll
    for (int nb = 0; nb < 2; ++nb) {
      const int n = (w * 2 + nb) * 16 + (lane & 15);
      const float bias = bbig[n];
      #pragma unroll
      for (int r = 0; r < 4; ++r) {
        const int row = (lane >> 4) * 4 + r;
        ust[row * 264 + n] = (ushort)f2bf(acc[nb][r] + bias);
      }
    }
  }
  __syncthreads();
  // phase 4: cross-sensor score tasks (uses prefetched sfeat); wave w handles 2
  {
    const uint* Au = (const uint*)shA;
    uint* Bu = (uint*)shB;
    #pragma unroll
    for (int jj = 0; jj < 2; ++jj) {
      const int j = w * 2 + jj;
      const uint ua = Au[j * 132 + lane * 2];
      const uint ub = Au[j * 132 + lane * 2 + 1];
      const float u0 = bflo(ua), u1 = bfhi(ua), u2 = bflo(ub), u3 = bfhi(ub);
      float scm[MM]; int anyv = 0;
      #pragma unroll
      for (int m = 0; m < MM; ++m) {
        const fvec4 sf = psf[jj][m];
        const int mk = mlds[j * MM + m];
        anyv |= mk;
        float p = sf.x * u0 + sf.y * u1 + sf.z * u2 + sf.w * u3;
        p = wred(p);
        scm[m] = mk ? p * 0.0625f : -1e9f;
      }
      float mx = scm[0];
      #pragma unroll
      for (int m = 1; m < MM; ++m) mx = fmaxf(mx, scm[m]);
      float e[MM], sum = 0.f;
      #pragma unroll
      for (int m = 0; m < MM; ++m) { e[m] = __expf(scm[m] - mx); sum += e[m]; }
      const float inv = 1.f / sum;
      fvec4 ag = (fvec4){0.f, 0.f, 0.f, 0.f};
      #pragma unroll
      for (int m = 0; m < MM; ++m) ag += (e[m] * inv) * psf[jj][m];
      Bu[j * 132 + lane * 2]     = bfpack(ag.x, ag.y);
      Bu[j * 132 + lane * 2 + 1] = bfpack(ag.z, ag.w);
      if (lane == 0) vlds[j] = anyv;
    }
  }
  __syncthreads();
  // phase 5: out = cagg @ Wvoc + bvoc -> Ost (shA+8448)
  {
    f32x4 acc[2];
    acc[0] = (f32x4){0.f, 0.f, 0.f, 0.f};
    acc[1] = (f32x4){0.f, 0.f, 0.f, 0.f};
    const char* cbase = shB + (lane & 15) * 528 + (lane >> 4) * 16;
    #pragma unroll
    for (int kb = 0; kb < 8; ++kb) {
      const bf16x8 a = *(const bf16x8*)(cbase + kb * 64);
      #pragma unroll
      for (int nb = 0; nb < 2; ++nb) {
        const bf16x8 bb = wvocpk[((w * 2 + nb) * 8 + kb) * 64 + lane];
        acc[nb] = mfma16(a, bb, acc[nb]);
      }
    }
    float* ost = (float*)(shA + 8448);
    #pragma unroll
    for (int nb = 0; nb < 2; ++nb) {
      const int n = (w * 2 + nb) * 16 + (lane & 15);
      const float bias = bvoc[n];
      #pragma unroll
      for (int r = 0; r < 4; ++r) {
        const int row = (lane >> 4) * 4 + r;
        ost[row * 260 + n] = acc[nb][r] + bias;
      }
    }
  }
  __syncthreads();
  {
    const float* ost = (const float*)(shA + 8448);
    #pragma unroll
    for (int it = 0; it < 8; ++it) {
      const int idx = it * 512 + t;
      const int row = idx >> 8, d = idx & 255;
      const float v = vlds[row] ? ost[row * 260 + d] : 0.f;
      __builtin_nontemporal_store(v, &out[((size_t)(g0 + row)) * 256 + d]);
    }
  }
}

extern "C" void kernel_launch(void* const* d_in, const int* in_sizes, int n_in,
                              void* d_out, int out_size, void* d_ws, size_t ws_size,
                              hipStream_t stream) {
  const float* ptsf  = (const float*)d_in[0];
  const float* ptspe = (const float*)d_in[1];
  const float* knnf  = (const float*)d_in[2];
  const float* knnpe = (const float*)d_in[3];
  const float* sfeat = (const float*)d_in[4];
  const int*   maskp = (const int*)d_in[5];
  const float* Wq_t = (const float*)d_in[6];
  const float* Wk_t = (const float*)d_in[7];
  const float* Wv_t = (const float*)d_in[8];
  const float* Wo_t = (const float*)d_in[9];
  const float* bq_t = (const float*)d_in[10];
  const float* bv_t = (const float*)d_in[12];
  const float* bo_t = (const float*)d_in[13];
  const float* Wq_c = (const float*)d_in[14];
  const float* Wk_c = (const float*)d_in[15];
  const float* Wv_c = (const float*)d_in[16];
  const float* Wo_c = (const float*)d_in[17];
  const float* bq_c = (const float*)d_in[18];
  const float* bv_c = (const float*)d_in[20];
  const float* bo_c = (const float*)d_in[21];
  // bk_t/bk_c unused: folded score constants are softmax-shift-invariant

  if (ws_size < WS_NEED) return;
  char* ws = (char*)d_ws;
  uint4* qk3pk  = (uint4*)(ws + OFF_QK3PK);
  uint4* wbigpk = (uint4*)(ws + OFF_WBIGPK);
  uint4* wvocpk = (uint4*)(ws + OFF_WVOCPK);
  float* bqk    = (float*)(ws + OFF_BQK);
  float* bbig   = (float*)(ws + OFF_BBIG);
  float* bvoc   = (float*)(ws + OFF_BVOC);

  prep_all<<<228, 256, 0, stream>>>(
      Wq_t, Wq_c, Wk_t, Wk_c, Wv_t, Wv_c, Wo_t, Wo_c,
      bq_t, bq_c, bv_t, bv_c, bo_t, bo_c,
      qk3pk, wbigpk, wvocpk, bqk, bbig, bvoc);

  stftr_mega<<<NBLK, 512, 0, stream>>>(
      ptsf, ptspe, knnf, knnpe, sfeat, maskp,
      (const bf16x8*)qk3pk, (const bf16x8*)wbigpk, (const bf16x8*)wvocpk,
      bqk, bbig, bvoc, (float*)d_out);
}

// Round 11
// 180.602 us; speedup vs baseline: 1.0227x; 1.0227x over previous
//
#include <hip/hip_runtime.h>
#include <math.h>

#define CC 256
#define KK 8
#define MM 6
#define SS 3
#define NVOX 12000
#define VB 16
#define NBLK (NVOX / VB)

typedef __attribute__((ext_vector_type(8))) short bf16x8;
typedef __attribute__((ext_vector_type(4))) float f32x4;
typedef __attribute__((ext_vector_type(4))) float fvec4;

// ---- ws layout (bytes) ----
#define OFF_QK3PK  0u           // uint4 [48ng][8kb][64lane]
#define OFF_WBIGPK 393216u      // uint4 [16ng][24kb][64lane]
#define OFF_WVOCPK 786432u      // uint4 [16ng][8kb][64lane]
#define OFF_BQK    917504u      // f32 [3][256]
#define OFF_BBIG   920576u      // f32 [256]
#define OFF_BVOC   921600u      // f32 [256]
#define WS_NEED    922624u

__device__ __forceinline__ float wred(float p) {
  #pragma unroll
  for (int off = 32; off; off >>= 1) p += __shfl_xor(p, off, 64);
  return p;
}
__device__ __forceinline__ uint f2bf(float x) {  // RNE to bf16 bits
  const uint u = __float_as_uint(x);
  return (u + 0x7fffu + ((u >> 16) & 1u)) >> 16;
}
__device__ __forceinline__ uint bfpack(float a, float b) {
  return (f2bf(b) << 16) | f2bf(a);
}
__device__ __forceinline__ float bflo(uint w) { return __uint_as_float(w << 16); }
__device__ __forceinline__ float bfhi(uint w) { return __uint_as_float(w & 0xffff0000u); }

__device__ __forceinline__ f32x4 mfma16(bf16x8 a, bf16x8 b, f32x4 c) {
  return __builtin_amdgcn_mfma_f32_16x16x32_bf16(a, b, c, 0, 0, 0);
}

// ---------------- single prep kernel: all folds, packed outputs ----------------
__global__ __launch_bounds__(256) void prep_all(
    const float* __restrict__ Wq_t, const float* __restrict__ Wq_c,
    const float* __restrict__ Wk_t, const float* __restrict__ Wk_c,
    const float* __restrict__ Wv_t, const float* __restrict__ Wv_c,
    const float* __restrict__ Wo_t, const float* __restrict__ Wo_c,
    const float* __restrict__ bq_t, const float* __restrict__ bq_c,
    const float* __restrict__ bv_t, const float* __restrict__ bv_c,
    const float* __restrict__ bo_t, const float* __restrict__ bo_c,
    uint4* __restrict__ qk3pk, uint4* __restrict__ wbigpk,
    uint4* __restrict__ wvocpk,
    float* __restrict__ bqk, float* __restrict__ bbig,
    float* __restrict__ bvoc) {
  const int b = blockIdx.x, t = threadIdx.x;
  __shared__ float xl[8][256];
  if (b < 96) {
    const int u = b >> 5, c0 = (b & 31) * 8;
    const float* Wq = Wq_t + u * 65536;
    const float* Wk = Wk_t + u * 65536;
    #pragma unroll
    for (int i = 0; i < 8; ++i) xl[i][t] = Wq[(c0 + i) * 256 + t];
    __syncthreads();
    float acc[8] = {0.f, 0.f, 0.f, 0.f, 0.f, 0.f, 0.f, 0.f};
    const float4* wr = (const float4*)(Wk + t * 256);
    #pragma unroll 4
    for (int d4 = 0; d4 < 64; ++d4) {
      const float4 wv = wr[d4];
      #pragma unroll
      for (int j = 0; j < 8; ++j)
        acc[j] += xl[j][d4 * 4] * wv.x + xl[j][d4 * 4 + 1] * wv.y +
                  xl[j][d4 * 4 + 2] * wv.z + xl[j][d4 * 4 + 3] * wv.w;
    }
    const int lane = (((c0 >> 3) & 3) << 4) | (t & 15);
    uint4 o;
    o.x = bfpack(acc[0], acc[1]); o.y = bfpack(acc[2], acc[3]);
    o.z = bfpack(acc[4], acc[5]); o.w = bfpack(acc[6], acc[7]);
    qk3pk[((u * 16 + (t >> 4)) * 8 + (c0 >> 5)) * 64 + lane] = o;
  } else if (b < 192) {
    const int v = (b - 96) >> 5, bi = (b - 96) & 31;
    const int c0 = bi * 8, row0 = v * 256 + c0;
    const float* Wv = Wv_t + v * 65536;
    const float* Wo = Wo_t + v * 65536;
    #pragma unroll
    for (int i = 0; i < 8; ++i) xl[i][t] = Wv[(c0 + i) * 256 + t];
    __syncthreads();
    float a1[8] = {0.f, 0.f, 0.f, 0.f, 0.f, 0.f, 0.f, 0.f};
    #pragma unroll 4
    for (int d = 0; d < 256; ++d) {
      const float w = Wo[d * 256 + t];
      #pragma unroll
      for (int j = 0; j < 8; ++j) a1[j] += xl[j][d] * w;
    }
    __syncthreads();
    #pragma unroll
    for (int j = 0; j < 8; ++j) xl[j][t] = a1[j];
    __syncthreads();
    float a2[8] = {0.f, 0.f, 0.f, 0.f, 0.f, 0.f, 0.f, 0.f};
    #pragma unroll 4
    for (int d = 0; d < 256; ++d) {
      const float w = Wq_c[d * 256 + t];
      #pragma unroll
      for (int j = 0; j < 8; ++j) a2[j] += xl[j][d] * w;
    }
    __syncthreads();
    #pragma unroll
    for (int j = 0; j < 8; ++j) xl[j][t] = a2[j];
    __syncthreads();
    float a3[8] = {0.f, 0.f, 0.f, 0.f, 0.f, 0.f, 0.f, 0.f};
    const float4* wr = (const float4*)(Wk_c + t * 256);
    #pragma unroll 4
    for (int d4 = 0; d4 < 64; ++d4) {
      const float4 wv = wr[d4];
      #pragma unroll
      for (int j = 0; j < 8; ++j)
        a3[j] += xl[j][d4 * 4] * wv.x + xl[j][d4 * 4 + 1] * wv.y +
                 xl[j][d4 * 4 + 2] * wv.z + xl[j][d4 * 4 + 3] * wv.w;
    }
    const int lane = (((row0 >> 3) & 3) << 4) | (t & 15);
    uint4 o;
    o.x = bfpack(a3[0], a3[1]); o.y = bfpack(a3[2], a3[3]);
    o.z = bfpack(a3[4], a3[5]); o.w = bfpack(a3[6], a3[7]);
    wbigpk[((t >> 4) * 24 + (row0 >> 5)) * 64 + lane] = o;
  } else if (b < 224) {
    const int c0 = (b - 192) * 8;
    #pragma unroll
    for (int i = 0; i < 8; ++i) xl[i][t] = Wv_c[(c0 + i) * 256 + t];
    __syncthreads();
    float acc[8] = {0.f, 0.f, 0.f, 0.f, 0.f, 0.f, 0.f, 0.f};
    #pragma unroll 4
    for (int d = 0; d < 256; ++d) {
      const float w = Wo_c[d * 256 + t];
      #pragma unroll
      for (int j = 0; j < 8; ++j) acc[j] += xl[j][d] * w;
    }
    const int lane = (((c0 >> 3) & 3) << 4) | (t & 15);
    uint4 o;
    o.x = bfpack(acc[0], acc[1]); o.y = bfpack(acc[2], acc[3]);
    o.z = bfpack(acc[4], acc[5]); o.w = bfpack(acc[6], acc[7]);
    wvocpk[((t >> 4) * 8 + (c0 >> 5)) * 64 + lane] = o;
  } else if (b < 227) {
    const int u = b - 224;
    xl[0][t] = bq_t[u * 256 + t];
    __syncthreads();
    const float4* wr = (const float4*)(Wk_t + u * 65536 + t * 256);
    float a = 0.f;
    #pragma unroll 4
    for (int d4 = 0; d4 < 64; ++d4) {
      const float4 wv = wr[d4];
      a += xl[0][d4 * 4] * wv.x + xl[0][d4 * 4 + 1] * wv.y +
           xl[0][d4 * 4 + 2] * wv.z + xl[0][d4 * 4 + 3] * wv.w;
    }
    bqk[u * 256 + t] = a;
  } else {
    xl[0][t] = bv_t[t]; xl[1][t] = bv_t[256 + t];
    xl[2][t] = bv_t[512 + t]; xl[3][t] = bv_c[t];
    __syncthreads();
    float bvs = bo_t[t] + bo_t[256 + t] + bo_t[512 + t];
    float bvc = bo_c[t];
    #pragma unroll 2
    for (int d = 0; d < 256; ++d) {
      bvs += xl[0][d] * Wo_t[d * 256 + t] +
             xl[1][d] * Wo_t[65536 + d * 256 + t] +
             xl[2][d] * Wo_t[131072 + d * 256 + t];
      bvc += xl[3][d] * Wo_c[d * 256 + t];
    }
    bvoc[t] = bvc;
    __syncthreads();
    xl[4][t] = bvs;
    __syncthreads();
    float y = bq_c[t];
    #pragma unroll 4
    for (int d = 0; d < 256; ++d) y += xl[4][d] * Wq_c[d * 256 + t];
    __syncthreads();
    xl[5][t] = y;
    __syncthreads();
    const float4* wr = (const float4*)(Wk_c + t * 256);
    float bb = 0.f;
    #pragma unroll 4
    for (int d4 = 0; d4 < 64; ++d4) {
      const float4 wv = wr[d4];
      bb += xl[5][d4 * 4] * wv.x + xl[5][d4 * 4 + 1] * wv.y +
            xl[5][d4 * 4 + 2] * wv.z + xl[5][d4 * 4 + 3] * wv.w;
    }
    bbig[t] = bb;
  }
}

// ---------------- mega kernel: R8 structure, in-place U/wagg, 4 blocks/CU ----------------
// shA [16][776] bf16: U (ph1b) -> wagg IN-PLACE (ph2) -> dead; cagg [16][264] @0 (ph4->ph5);
//                     Ost f32[16][260] @8448 (ph5->store)
// shB [16][264] bf16: qb (ph0->ph1b); Uc (ph3->ph4)
__global__ __launch_bounds__(512, 8) void stftr_mega(
    const float* __restrict__ ptsf, const float* __restrict__ ptspe,
    const float* __restrict__ knnf, const float* __restrict__ knnpe,
    const float* __restrict__ sfeat, const int* __restrict__ maskp,
    const bf16x8* __restrict__ qk3pk, const bf16x8* __restrict__ wbigpk,
    const bf16x8* __restrict__ wvocpk,
    const float* __restrict__ bqk, const float* __restrict__ bbig,
    const float* __restrict__ bvoc,
    float* __restrict__ out) {
  __shared__ char shA[25088];
  __shared__ char shB[8448];
  __shared__ int mlds[VB * MM];
  __shared__ int vlds[VB];
  const int t = threadIdx.x, lane = t & 63, w = t >> 6;
  const int g0 = blockIdx.x * VB;
  const fvec4* kfp = (const fvec4*)knnf;
  const fvec4* kpp = (const fvec4*)knnpe;
  const fvec4* sfp = (const fvec4*)sfeat;

  // phase 1a: stage qb = bf16(ptsf+ptspe) into shB ; preload mask
  {
    uint* qb_u = (uint*)shB;
    const fvec4* a4 = (const fvec4*)(ptsf + (size_t)g0 * CC);
    const fvec4* b4 = (const fvec4*)(ptspe + (size_t)g0 * CC);
    #pragma unroll
    for (int it = 0; it < 2; ++it) {
      const int idx = it * 512 + t;
      const int row = idx >> 6, c4 = idx & 63;
      const fvec4 va = __builtin_nontemporal_load(&a4[idx]);
      const fvec4 vb = __builtin_nontemporal_load(&b4[idx]);
      qb_u[row * 132 + c4 * 2]     = bfpack(va.x + vb.x, va.y + vb.y);
      qb_u[row * 132 + c4 * 2 + 1] = bfpack(va.z + vb.z, va.w + vb.w);
    }
    if (t < VB * MM) mlds[t] = maskp[g0 * MM + t];
  }
  __syncthreads();
  // phase 1b: U = qb @ Wqk3 + bqk  (N=768) -> shA
  {
    f32x4 acc[6];
    #pragma unroll
    for (int nb = 0; nb < 6; ++nb) acc[nb] = (f32x4){0.f, 0.f, 0.f, 0.f};
    const char* qbase = shB + (lane & 15) * 528 + (lane >> 4) * 16;
    #pragma unroll
    for (int kb = 0; kb < 8; ++kb) {
      const bf16x8 a = *(const bf16x8*)(qbase + kb * 64);
      #pragma unroll
      for (int nb = 0; nb < 6; ++nb) {
        const bf16x8 bb = qk3pk[((w * 6 + nb) * 8 + kb) * 64 + lane];
        acc[nb] = mfma16(a, bb, acc[nb]);
      }
    }
    ushort* us = (ushort*)shA;
    #pragma unroll
    for (int nb = 0; nb < 6; ++nb) {
      const int n = (w * 6 + nb) * 16 + (lane & 15);
      const float bias = bqk[n];
      #pragma unroll
      for (int r = 0; r < 4; ++r) {
        const int row = (lane >> 4) * 4 + r;
        us[row * 776 + n] = (ushort)f2bf(acc[nb][r] + bias);
      }
    }
  }
  __syncthreads();
  // phase 2: 48 temporal score tasks; wave w handles 6. Reads U row, writes
  // wagg IN-PLACE into the same (s,j) row (row fully consumed before write).
  {
    uint* AB = (uint*)shA;
    for (int q = 0; q < 6; ++q) {
      const int tid = w * 6 + q;
      const int s = tid >> 4, j = tid & 15;
      const size_t rb = ((size_t)(s * NVOX + g0 + j)) * 512 + lane;
      fvec4 sm[KK];
      #pragma unroll
      for (int r = 0; r < KK; ++r) {
        const fvec4 kf = __builtin_nontemporal_load(&kfp[rb + r * 64]);
        const fvec4 kp = __builtin_nontemporal_load(&kpp[rb + r * 64]);
        sm[r] = kf + kp;
      }
      const uint ua = AB[j * 388 + s * 128 + lane * 2];
      const uint ub = AB[j * 388 + s * 128 + lane * 2 + 1];
      const float u0 = bflo(ua), u1 = bfhi(ua), u2 = bflo(ub), u3 = bfhi(ub);
      float sc[KK];
      #pragma unroll
      for (int r = 0; r < KK; ++r) {
        float p = sm[r].x * u0 + sm[r].y * u1 + sm[r].z * u2 + sm[r].w * u3;
        sc[r] = wred(p);
      }
      float mx = sc[0];
      #pragma unroll
      for (int r = 1; r < KK; ++r) mx = fmaxf(mx, sc[r]);
      float e[KK], sum = 0.f;
      #pragma unroll
      for (int r = 0; r < KK; ++r) { e[r] = __expf((sc[r] - mx) * 0.0625f); sum += e[r]; }
      const float inv = 1.f / sum;
      fvec4 acc = (fvec4){0.f, 0.f, 0.f, 0.f};
      #pragma unroll
      for (int r = 0; r < KK; ++r) acc += (e[r] * inv) * sm[r];
      AB[j * 388 + s * 128 + lane * 2]     = bfpack(acc.x, acc.y);
      AB[j * 388 + s * 128 + lane * 2 + 1] = bfpack(acc.z, acc.w);
    }
  }
  __syncthreads();
  // phase 3: Uc = wagg_cat @ Wbig + bbig  (K=768, N=256) -> shB (qb dead)
  {
    f32x4 acc[2];
    acc[0] = (f32x4){0.f, 0.f, 0.f, 0.f};
    acc[1] = (f32x4){0.f, 0.f, 0.f, 0.f};
    const char* abase = shA + (lane & 15) * 1552 + (lane >> 4) * 16;
    #pragma unroll 4
    for (int kb = 0; kb < 24; ++kb) {
      const bf16x8 a = *(const bf16x8*)(abase + kb * 64);
      #pragma unroll
      for (int nb = 0; nb < 2; ++nb) {
        const bf16x8 bb = wbigpk[((w * 2 + nb) * 24 + kb) * 64 + lane];
        acc[nb] = mfma16(a, bb, acc[nb]);
      }
    }
    ushort* ust = (ushort*)shB;
    #pragma unroll
    for (int nb = 0; nb < 2; ++nb) {
      const int n = (w * 2 + nb) * 16 + (lane & 15);
      const float bias = bbig[n];
      #pragma unroll
      for (int r = 0; r < 4; ++r) {
        const int row = (lane >> 4) * 4 + r;
        ust[row * 264 + n] = (ushort)f2bf(acc[nb][r] + bias);
      }
    }
  }
  __syncthreads();
  // phase 4: cross-sensor score tasks; wave w handles 2; cagg -> shA (dead)
  {
    const uint* Au = (const uint*)shB;
    uint* Bu = (uint*)shA;
    #pragma unroll
    for (int jj = 0; jj < 2; ++jj) {
      const int j = w * 2 + jj;
      const int g = g0 + j;
      const uint ua = Au[j * 132 + lane * 2];
      const uint ub = Au[j * 132 + lane * 2 + 1];
      const float u0 = bflo(ua), u1 = bfhi(ua), u2 = bflo(ub), u3 = bfhi(ub);
      const size_t sb = (size_t)g * (MM * 64) + lane;
      fvec4 sf[MM]; float scm[MM]; int anyv = 0;
      #pragma unroll
      for (int m = 0; m < MM; ++m) {
        sf[m] = __builtin_nontemporal_load(&sfp[sb + m * 64]);
        const int mk = mlds[j * MM + m];
        anyv |= mk;
        float p = sf[m].x * u0 + sf[m].y * u1 + sf[m].z * u2 + sf[m].w * u3;
        p = wred(p);
        scm[m] = mk ? p * 0.0625f : -1e9f;
      }
      float mx = scm[0];
      #pragma unroll
      for (int m = 1; m < MM; ++m) mx = fmaxf(mx, scm[m]);
      float e[MM], sum = 0.f;
      #pragma unroll
      for (int m = 0; m < MM; ++m) { e[m] = __expf(scm[m] - mx); sum += e[m]; }
      const float inv = 1.f / sum;
      fvec4 ag = (fvec4){0.f, 0.f, 0.f, 0.f};
      #pragma unroll
      for (int m = 0; m < MM; ++m) ag += (e[m] * inv) * sf[m];
      Bu[j * 132 + lane * 2]     = bfpack(ag.x, ag.y);
      Bu[j * 132 + lane * 2 + 1] = bfpack(ag.z, ag.w);
      if (lane == 0) vlds[j] = anyv;
    }
  }
  __syncthreads();
  // phase 5: out = cagg @ Wvoc + bvoc -> Ost (shA+8448)
  {
    f32x4 acc[2];
    acc[0] = (f32x4){0.f, 0.f, 0.f, 0.f};
    acc[1] = (f32x4){0.f, 0.f, 0.f, 0.f};
    const char* cbase = shA + (lane & 15) * 528 + (lane >> 4) * 16;
    #pragma unroll
    for (int kb = 0; kb < 8; ++kb) {
      const bf16x8 a = *(const bf16x8*)(cbase + kb * 64);
      #pragma unroll
      for (int nb = 0; nb < 2; ++nb) {
        const bf16x8 bb = wvocpk[((w * 2 + nb) * 8 + kb) * 64 + lane];
        acc[nb] = mfma16(a, bb, acc[nb]);
      }
    }
    float* ost = (float*)(shA + 8448);
    #pragma unroll
    for (int nb = 0; nb < 2; ++nb) {
      const int n = (w * 2 + nb) * 16 + (lane & 15);
      const float bias = bvoc[n];
      #pragma unroll
      for (int r = 0; r < 4; ++r) {
        const int row = (lane >> 4) * 4 + r;
        ost[row * 260 + n] = acc[nb][r] + bias;
      }
    }
  }
  __syncthreads();
  {
    const float* ost = (const float*)(shA + 8448);
    #pragma unroll
    for (int it = 0; it < 8; ++it) {
      const int idx = it * 512 + t;
      const int row = idx >> 8, d = idx & 255;
      const float v = vlds[row] ? ost[row * 260 + d] : 0.f;
      __builtin_nontemporal_store(v, &out[((size_t)(g0 + row)) * 256 + d]);
    }
  }
}

extern "C" void kernel_launch(void* const* d_in, const int* in_sizes, int n_in,
                              void* d_out, int out_size, void* d_ws, size_t ws_size,
                              hipStream_t stream) {
  const float* ptsf  = (const float*)d_in[0];
  const float* ptspe = (const float*)d_in[1];
  const float* knnf  = (const float*)d_in[2];
  const float* knnpe = (const float*)d_in[3];
  const float* sfeat = (const float*)d_in[4];
  const int*   maskp = (const int*)d_in[5];
  const float* Wq_t = (const float*)d_in[6];
  const float* Wk_t = (const float*)d_in[7];
  const float* Wv_t = (const float*)d_in[8];
  const float* Wo_t = (const float*)d_in[9];
  const float* bq_t = (const float*)d_in[10];
  const float* bv_t = (const float*)d_in[12];
  const float* bo_t = (const float*)d_in[13];
  const float* Wq_c = (const float*)d_in[14];
  const float* Wk_c = (const float*)d_in[15];
  const float* Wv_c = (const float*)d_in[16];
  const float* Wo_c = (const float*)d_in[17];
  const float* bq_c = (const float*)d_in[18];
  const float* bv_c = (const float*)d_in[20];
  const float* bo_c = (const float*)d_in[21];
  // bk_t/bk_c unused: folded score constants are softmax-shift-invariant

  if (ws_size < WS_NEED) return;
  char* ws = (char*)d_ws;
  uint4* qk3pk  = (uint4*)(ws + OFF_QK3PK);
  uint4* wbigpk = (uint4*)(ws + OFF_WBIGPK);
  uint4* wvocpk = (uint4*)(ws + OFF_WVOCPK);
  float* bqk    = (float*)(ws + OFF_BQK);
  float* bbig   = (float*)(ws + OFF_BBIG);
  float* bvoc   = (float*)(ws + OFF_BVOC);

  prep_all<<<228, 256, 0, stream>>>(
      Wq_t, Wq_c, Wk_t, Wk_c, Wv_t, Wv_c, Wo_t, Wo_c,
      bq_t, bq_c, bv_t, bv_c, bo_t, bo_c,
      qk3pk, wbigpk, wvocpk, bqk, bbig, bvoc);

  stftr_mega<<<NBLK, 512, 0, stream>>>(
      ptsf, ptspe, knnf, knnpe, sfeat, maskp,
      (const bf16x8*)qk3pk, (const bf16x8*)wbigpk, (const bf16x8*)wvocpk,
      bqk, bbig, bvoc, (float*)d_out);
}

// Round 12
// 168.416 us; speedup vs baseline: 1.0967x; 1.0724x over previous
//
#include <hip/hip_runtime.h>
#include <math.h>

#define CC 256
#define KK 8
#define MM 6
#define SS 3
#define NVOX 12000
#define VB 16
#define NBLK (NVOX / VB)

typedef __attribute__((ext_vector_type(8))) short bf16x8;
typedef __attribute__((ext_vector_type(4))) float f32x4;
typedef __attribute__((ext_vector_type(4))) float fvec4;

// ---- ws layout (bytes) ----
#define OFF_QK3PK  0u           // uint4 [48ng][8kb][64lane]
#define OFF_WBIGPK 393216u      // uint4 [16ng][24kb][64lane]
#define OFF_WVOCPK 786432u      // uint4 [16ng][8kb][64lane]
#define OFF_BQK    917504u      // f32 [3][256]
#define OFF_BBIG   920576u      // f32 [256]
#define OFF_BVOC   921600u      // f32 [256]
#define WS_NEED    922624u

__device__ __forceinline__ float wred(float p) {
  #pragma unroll
  for (int off = 32; off; off >>= 1) p += __shfl_xor(p, off, 64);
  return p;
}
__device__ __forceinline__ uint f2bf(float x) {  // RNE to bf16 bits
  const uint u = __float_as_uint(x);
  return (u + 0x7fffu + ((u >> 16) & 1u)) >> 16;
}
__device__ __forceinline__ uint bfpack(float a, float b) {
  return (f2bf(b) << 16) | f2bf(a);
}
__device__ __forceinline__ float bflo(uint w) { return __uint_as_float(w << 16); }
__device__ __forceinline__ float bfhi(uint w) { return __uint_as_float(w & 0xffff0000u); }

__device__ __forceinline__ f32x4 mfma16(bf16x8 a, bf16x8 b, f32x4 c) {
  return __builtin_amdgcn_mfma_f32_16x16x32_bf16(a, b, c, 0, 0, 0);
}

// ---------------- single prep kernel: all folds, packed outputs ----------------
__global__ __launch_bounds__(256) void prep_all(
    const float* __restrict__ Wq_t, const float* __restrict__ Wq_c,
    const float* __restrict__ Wk_t, const float* __restrict__ Wk_c,
    const float* __restrict__ Wv_t, const float* __restrict__ Wv_c,
    const float* __restrict__ Wo_t, const float* __restrict__ Wo_c,
    const float* __restrict__ bq_t, const float* __restrict__ bq_c,
    const float* __restrict__ bv_t, const float* __restrict__ bv_c,
    const float* __restrict__ bo_t, const float* __restrict__ bo_c,
    uint4* __restrict__ qk3pk, uint4* __restrict__ wbigpk,
    uint4* __restrict__ wvocpk,
    float* __restrict__ bqk, float* __restrict__ bbig,
    float* __restrict__ bvoc) {
  const int b = blockIdx.x, t = threadIdx.x;
  __shared__ float xl[8][256];
  if (b < 96) {
    const int u = b >> 5, c0 = (b & 31) * 8;
    const float* Wq = Wq_t + u * 65536;
    const float* Wk = Wk_t + u * 65536;
    #pragma unroll
    for (int i = 0; i < 8; ++i) xl[i][t] = Wq[(c0 + i) * 256 + t];
    __syncthreads();
    float acc[8] = {0.f, 0.f, 0.f, 0.f, 0.f, 0.f, 0.f, 0.f};
    const float4* wr = (const float4*)(Wk + t * 256);
    #pragma unroll 4
    for (int d4 = 0; d4 < 64; ++d4) {
      const float4 wv = wr[d4];
      #pragma unroll
      for (int j = 0; j < 8; ++j)
        acc[j] += xl[j][d4 * 4] * wv.x + xl[j][d4 * 4 + 1] * wv.y +
                  xl[j][d4 * 4 + 2] * wv.z + xl[j][d4 * 4 + 3] * wv.w;
    }
    const int lane = (((c0 >> 3) & 3) << 4) | (t & 15);
    uint4 o;
    o.x = bfpack(acc[0], acc[1]); o.y = bfpack(acc[2], acc[3]);
    o.z = bfpack(acc[4], acc[5]); o.w = bfpack(acc[6], acc[7]);
    qk3pk[((u * 16 + (t >> 4)) * 8 + (c0 >> 5)) * 64 + lane] = o;
  } else if (b < 192) {
    const int v = (b - 96) >> 5, bi = (b - 96) & 31;
    const int c0 = bi * 8, row0 = v * 256 + c0;
    const float* Wv = Wv_t + v * 65536;
    const float* Wo = Wo_t + v * 65536;
    #pragma unroll
    for (int i = 0; i < 8; ++i) xl[i][t] = Wv[(c0 + i) * 256 + t];
    __syncthreads();
    float a1[8] = {0.f, 0.f, 0.f, 0.f, 0.f, 0.f, 0.f, 0.f};
    #pragma unroll 4
    for (int d = 0; d < 256; ++d) {
      const float w = Wo[d * 256 + t];
      #pragma unroll
      for (int j = 0; j < 8; ++j) a1[j] += xl[j][d] * w;
    }
    __syncthreads();
    #pragma unroll
    for (int j = 0; j < 8; ++j) xl[j][t] = a1[j];
    __syncthreads();
    float a2[8] = {0.f, 0.f, 0.f, 0.f, 0.f, 0.f, 0.f, 0.f};
    #pragma unroll 4
    for (int d = 0; d < 256; ++d) {
      const float w = Wq_c[d * 256 + t];
      #pragma unroll
      for (int j = 0; j < 8; ++j) a2[j] += xl[j][d] * w;
    }
    __syncthreads();
    #pragma unroll
    for (int j = 0; j < 8; ++j) xl[j][t] = a2[j];
    __syncthreads();
    float a3[8] = {0.f, 0.f, 0.f, 0.f, 0.f, 0.f, 0.f, 0.f};
    const float4* wr = (const float4*)(Wk_c + t * 256);
    #pragma unroll 4
    for (int d4 = 0; d4 < 64; ++d4) {
      const float4 wv = wr[d4];
      #pragma unroll
      for (int j = 0; j < 8; ++j)
        a3[j] += xl[j][d4 * 4] * wv.x + xl[j][d4 * 4 + 1] * wv.y +
                 xl[j][d4 * 4 + 2] * wv.z + xl[j][d4 * 4 + 3] * wv.w;
    }
    const int lane = (((row0 >> 3) & 3) << 4) | (t & 15);
    uint4 o;
    o.x = bfpack(a3[0], a3[1]); o.y = bfpack(a3[2], a3[3]);
    o.z = bfpack(a3[4], a3[5]); o.w = bfpack(a3[6], a3[7]);
    wbigpk[((t >> 4) * 24 + (row0 >> 5)) * 64 + lane] = o;
  } else if (b < 224) {
    const int c0 = (b - 192) * 8;
    #pragma unroll
    for (int i = 0; i < 8; ++i) xl[i][t] = Wv_c[(c0 + i) * 256 + t];
    __syncthreads();
    float acc[8] = {0.f, 0.f, 0.f, 0.f, 0.f, 0.f, 0.f, 0.f};
    #pragma unroll 4
    for (int d = 0; d < 256; ++d) {
      const float w = Wo_c[d * 256 + t];
      #pragma unroll
      for (int j = 0; j < 8; ++j) acc[j] += xl[j][d] * w;
    }
    const int lane = (((c0 >> 3) & 3) << 4) | (t & 15);
    uint4 o;
    o.x = bfpack(acc[0], acc[1]); o.y = bfpack(acc[2], acc[3]);
    o.z = bfpack(acc[4], acc[5]); o.w = bfpack(acc[6], acc[7]);
    wvocpk[((t >> 4) * 8 + (c0 >> 5)) * 64 + lane] = o;
  } else if (b < 227) {
    const int u = b - 224;
    xl[0][t] = bq_t[u * 256 + t];
    __syncthreads();
    const float4* wr = (const float4*)(Wk_t + u * 65536 + t * 256);
    float a = 0.f;
    #pragma unroll 4
    for (int d4 = 0; d4 < 64; ++d4) {
      const float4 wv = wr[d4];
      a += xl[0][d4 * 4] * wv.x + xl[0][d4 * 4 + 1] * wv.y +
           xl[0][d4 * 4 + 2] * wv.z + xl[0][d4 * 4 + 3] * wv.w;
    }
    bqk[u * 256 + t] = a;
  } else {
    xl[0][t] = bv_t[t]; xl[1][t] = bv_t[256 + t];
    xl[2][t] = bv_t[512 + t]; xl[3][t] = bv_c[t];
    __syncthreads();
    float bvs = bo_t[t] + bo_t[256 + t] + bo_t[512 + t];
    float bvc = bo_c[t];
    #pragma unroll 2
    for (int d = 0; d < 256; ++d) {
      bvs += xl[0][d] * Wo_t[d * 256 + t] +
             xl[1][d] * Wo_t[65536 + d * 256 + t] +
             xl[2][d] * Wo_t[131072 + d * 256 + t];
      bvc += xl[3][d] * Wo_c[d * 256 + t];
    }
    bvoc[t] = bvc;
    __syncthreads();
    xl[4][t] = bvs;
    __syncthreads();
    float y = bq_c[t];
    #pragma unroll 4
    for (int d = 0; d < 256; ++d) y += xl[4][d] * Wq_c[d * 256 + t];
    __syncthreads();
    xl[5][t] = y;
    __syncthreads();
    const float4* wr = (const float4*)(Wk_c + t * 256);
    float bb = 0.f;
    #pragma unroll 4
    for (int d4 = 0; d4 < 64; ++d4) {
      const float4 wv = wr[d4];
      bb += xl[5][d4 * 4] * wv.x + xl[5][d4 * 4 + 1] * wv.y +
            xl[5][d4 * 4 + 2] * wv.z + xl[5][d4 * 4 + 3] * wv.w;
    }
    bbig[t] = bb;
  }
}

// ---------------- mega kernel: R8 register regime + in-place U/wagg LDS ----------------
// shA [16][776] bf16: U (ph1b) -> wagg IN-PLACE (ph2) -> dead; cagg [16][264] @0 (ph4->ph5);
//                     Ost f32[16][260] @8448 (ph5->store)
// shB [16][264] bf16: qb (ph0->ph1b); Uc (ph3->ph4)
__global__ __launch_bounds__(512, 6) void stftr_mega(
    const float* __restrict__ ptsf, const float* __restrict__ ptspe,
    const float* __restrict__ knnf, const float* __restrict__ knnpe,
    const float* __restrict__ sfeat, const int* __restrict__ maskp,
    const bf16x8* __restrict__ qk3pk, const bf16x8* __restrict__ wbigpk,
    const bf16x8* __restrict__ wvocpk,
    const float* __restrict__ bqk, const float* __restrict__ bbig,
    const float* __restrict__ bvoc,
    float* __restrict__ out) {
  __shared__ char shA[25088];
  __shared__ char shB[8448];
  __shared__ int mlds[VB * MM];
  __shared__ int vlds[VB];
  const int t = threadIdx.x, lane = t & 63, w = t >> 6;
  const int g0 = blockIdx.x * VB;
  const fvec4* kfp = (const fvec4*)knnf;
  const fvec4* kpp = (const fvec4*)knnpe;
  const fvec4* sfp = (const fvec4*)sfeat;

  // phase 1a: stage qb = bf16(ptsf+ptspe) into shB ; preload mask
  {
    uint* qb_u = (uint*)shB;
    const fvec4* a4 = (const fvec4*)(ptsf + (size_t)g0 * CC);
    const fvec4* b4 = (const fvec4*)(ptspe + (size_t)g0 * CC);
    #pragma unroll
    for (int it = 0; it < 2; ++it) {
      const int idx = it * 512 + t;
      const int row = idx >> 6, c4 = idx & 63;
      const fvec4 va = __builtin_nontemporal_load(&a4[idx]);
      const fvec4 vb = __builtin_nontemporal_load(&b4[idx]);
      qb_u[row * 132 + c4 * 2]     = bfpack(va.x + vb.x, va.y + vb.y);
      qb_u[row * 132 + c4 * 2 + 1] = bfpack(va.z + vb.z, va.w + vb.w);
    }
    if (t < VB * MM) mlds[t] = maskp[g0 * MM + t];
  }
  __syncthreads();
  // phase 1b: U = qb @ Wqk3 + bqk  (N=768) -> shA
  {
    f32x4 acc[6];
    #pragma unroll
    for (int nb = 0; nb < 6; ++nb) acc[nb] = (f32x4){0.f, 0.f, 0.f, 0.f};
    const char* qbase = shB + (lane & 15) * 528 + (lane >> 4) * 16;
    #pragma unroll
    for (int kb = 0; kb < 8; ++kb) {
      const bf16x8 a = *(const bf16x8*)(qbase + kb * 64);
      #pragma unroll
      for (int nb = 0; nb < 6; ++nb) {
        const bf16x8 bb = qk3pk[((w * 6 + nb) * 8 + kb) * 64 + lane];
        acc[nb] = mfma16(a, bb, acc[nb]);
      }
    }
    ushort* us = (ushort*)shA;
    #pragma unroll
    for (int nb = 0; nb < 6; ++nb) {
      const int n = (w * 6 + nb) * 16 + (lane & 15);
      const float bias = bqk[n];
      #pragma unroll
      for (int r = 0; r < 4; ++r) {
        const int row = (lane >> 4) * 4 + r;
        us[row * 776 + n] = (ushort)f2bf(acc[nb][r] + bias);
      }
    }
  }
  __syncthreads();
  // phase 2: 48 temporal score tasks; wave w handles 6. Reads U row, writes
  // wagg IN-PLACE into the same (s,j) row (row fully consumed before write).
  {
    uint* AB = (uint*)shA;
    for (int q = 0; q < 6; ++q) {
      const int tid = w * 6 + q;
      const int s = tid >> 4, j = tid & 15;
      const size_t rb = ((size_t)(s * NVOX + g0 + j)) * 512 + lane;
      fvec4 sm[KK];
      #pragma unroll
      for (int r = 0; r < KK; ++r) {
        const fvec4 kf = __builtin_nontemporal_load(&kfp[rb + r * 64]);
        const fvec4 kp = __builtin_nontemporal_load(&kpp[rb + r * 64]);
        sm[r] = kf + kp;
      }
      const uint ua = AB[j * 388 + s * 128 + lane * 2];
      const uint ub = AB[j * 388 + s * 128 + lane * 2 + 1];
      const float u0 = bflo(ua), u1 = bfhi(ua), u2 = bflo(ub), u3 = bfhi(ub);
      float sc[KK];
      #pragma unroll
      for (int r = 0; r < KK; ++r) {
        float p = sm[r].x * u0 + sm[r].y * u1 + sm[r].z * u2 + sm[r].w * u3;
        sc[r] = wred(p);
      }
      float mx = sc[0];
      #pragma unroll
      for (int r = 1; r < KK; ++r) mx = fmaxf(mx, sc[r]);
      float e[KK], sum = 0.f;
      #pragma unroll
      for (int r = 0; r < KK; ++r) { e[r] = __expf((sc[r] - mx) * 0.0625f); sum += e[r]; }
      const float inv = 1.f / sum;
      fvec4 acc = (fvec4){0.f, 0.f, 0.f, 0.f};
      #pragma unroll
      for (int r = 0; r < KK; ++r) acc += (e[r] * inv) * sm[r];
      AB[j * 388 + s * 128 + lane * 2]     = bfpack(acc.x, acc.y);
      AB[j * 388 + s * 128 + lane * 2 + 1] = bfpack(acc.z, acc.w);
    }
  }
  __syncthreads();
  // phase 3: Uc = wagg_cat @ Wbig + bbig  (K=768, N=256) -> shB (qb dead)
  {
    f32x4 acc[2];
    acc[0] = (f32x4){0.f, 0.f, 0.f, 0.f};
    acc[1] = (f32x4){0.f, 0.f, 0.f, 0.f};
    const char* abase = shA + (lane & 15) * 1552 + (lane >> 4) * 16;
    #pragma unroll 4
    for (int kb = 0; kb < 24; ++kb) {
      const bf16x8 a = *(const bf16x8*)(abase + kb * 64);
      #pragma unroll
      for (int nb = 0; nb < 2; ++nb) {
        const bf16x8 bb = wbigpk[((w * 2 + nb) * 24 + kb) * 64 + lane];
        acc[nb] = mfma16(a, bb, acc[nb]);
      }
    }
    ushort* ust = (ushort*)shB;
    #pragma unroll
    for (int nb = 0; nb < 2; ++nb) {
      const int n = (w * 2 + nb) * 16 + (lane & 15);
      const float bias = bbig[n];
      #pragma unroll
      for (int r = 0; r < 4; ++r) {
        const int row = (lane >> 4) * 4 + r;
        ust[row * 264 + n] = (ushort)f2bf(acc[nb][r] + bias);
      }
    }
  }
  __syncthreads();
  // phase 4: cross-sensor score tasks; wave w handles 2; cagg -> shA (dead)
  {
    const uint* Au = (const uint*)shB;
    uint* Bu = (uint*)shA;
    #pragma unroll
    for (int jj = 0; jj < 2; ++jj) {
      const int j = w * 2 + jj;
      const int g = g0 + j;
      const uint ua = Au[j * 132 + lane * 2];
      const uint ub = Au[j * 132 + lane * 2 + 1];
      const float u0 = bflo(ua), u1 = bfhi(ua), u2 = bflo(ub), u3 = bfhi(ub);
      const size_t sb = (size_t)g * (MM * 64) + lane;
      fvec4 sf[MM]; float scm[MM]; int anyv = 0;
      #pragma unroll
      for (int m = 0; m < MM; ++m) {
        sf[m] = __builtin_nontemporal_load(&sfp[sb + m * 64]);
        const int mk = mlds[j * MM + m];
        anyv |= mk;
        float p = sf[m].x * u0 + sf[m].y * u1 + sf[m].z * u2 + sf[m].w * u3;
        p = wred(p);
        scm[m] = mk ? p * 0.0625f : -1e9f;
      }
      float mx = scm[0];
      #pragma unroll
      for (int m = 1; m < MM; ++m) mx = fmaxf(mx, scm[m]);
      float e[MM], sum = 0.f;
      #pragma unroll
      for (int m = 0; m < MM; ++m) { e[m] = __expf(scm[m] - mx); sum += e[m]; }
      const float inv = 1.f / sum;
      fvec4 ag = (fvec4){0.f, 0.f, 0.f, 0.f};
      #pragma unroll
      for (int m = 0; m < MM; ++m) ag += (e[m] * inv) * sf[m];
      Bu[j * 132 + lane * 2]     = bfpack(ag.x, ag.y);
      Bu[j * 132 + lane * 2 + 1] = bfpack(ag.z, ag.w);
      if (lane == 0) vlds[j] = anyv;
    }
  }
  __syncthreads();
  // phase 5: out = cagg @ Wvoc + bvoc -> Ost (shA+8448)
  {
    f32x4 acc[2];
    acc[0] = (f32x4){0.f, 0.f, 0.f, 0.f};
    acc[1] = (f32x4){0.f, 0.f, 0.f, 0.f};
    const char* cbase = shA + (lane & 15) * 528 + (lane >> 4) * 16;
    #pragma unroll
    for (int kb = 0; kb < 8; ++kb) {
      const bf16x8 a = *(const bf16x8*)(cbase + kb * 64);
      #pragma unroll
      for (int nb = 0; nb < 2; ++nb) {
        const bf16x8 bb = wvocpk[((w * 2 + nb) * 8 + kb) * 64 + lane];
        acc[nb] = mfma16(a, bb, acc[nb]);
      }
    }
    float* ost = (float*)(shA + 8448);
    #pragma unroll
    for (int nb = 0; nb < 2; ++nb) {
      const int n = (w * 2 + nb) * 16 + (lane & 15);
      const float bias = bvoc[n];
      #pragma unroll
      for (int r = 0; r < 4; ++r) {
        const int row = (lane >> 4) * 4 + r;
        ost[row * 260 + n] = acc[nb][r] + bias;
      }
    }
  }
  __syncthreads();
  {
    const float* ost = (const float*)(shA + 8448);
    #pragma unroll
    for (int it = 0; it < 8; ++it) {
      const int idx = it * 512 + t;
      const int row = idx >> 8, d = idx & 255;
      const float v = vlds[row] ? ost[row * 260 + d] : 0.f;
      __builtin_nontemporal_store(v, &out[((size_t)(g0 + row)) * 256 + d]);
    }
  }
}

extern "C" void kernel_launch(void* const* d_in, const int* in_sizes, int n_in,
                              void* d_out, int out_size, void* d_ws, size_t ws_size,
                              hipStream_t stream) {
  const float* ptsf  = (const float*)d_in[0];
  const float* ptspe = (const float*)d_in[1];
  const float* knnf  = (const float*)d_in[2];
  const float* knnpe = (const float*)d_in[3];
  const float* sfeat = (const float*)d_in[4];
  const int*   maskp = (const int*)d_in[5];
  const float* Wq_t = (const float*)d_in[6];
  const float* Wk_t = (const float*)d_in[7];
  const float* Wv_t = (const float*)d_in[8];
  const float* Wo_t = (const float*)d_in[9];
  const float* bq_t = (const float*)d_in[10];
  const float* bv_t = (const float*)d_in[12];
  const float* bo_t = (const float*)d_in[13];
  const float* Wq_c = (const float*)d_in[14];
  const float* Wk_c = (const float*)d_in[15];
  const float* Wv_c = (const float*)d_in[16];
  const float* Wo_c = (const float*)d_in[17];
  const float* bq_c = (const float*)d_in[18];
  const float* bv_c = (const float*)d_in[20];
  const float* bo_c = (const float*)d_in[21];
  // bk_t/bk_c unused: folded score constants are softmax-shift-invariant

  if (ws_size < WS_NEED) return;
  char* ws = (char*)d_ws;
  uint4* qk3pk  = (uint4*)(ws + OFF_QK3PK);
  uint4* wbigpk = (uint4*)(ws + OFF_WBIGPK);
  uint4* wvocpk = (uint4*)(ws + OFF_WVOCPK);
  float* bqk    = (float*)(ws + OFF_BQK);
  float* bbig   = (float*)(ws + OFF_BBIG);
  float* bvoc   = (float*)(ws + OFF_BVOC);

  prep_all<<<228, 256, 0, stream>>>(
      Wq_t, Wq_c, Wk_t, Wk_c, Wv_t, Wv_c, Wo_t, Wo_c,
      bq_t, bq_c, bv_t, bv_c, bo_t, bo_c,
      qk3pk, wbigpk, wvocpk, bqk, bbig, bvoc);

  stftr_mega<<<NBLK, 512, 0, stream>>>(
      ptsf, ptspe, knnf, knnpe, sfeat, maskp,
      (const bf16x8*)qk3pk, (const bf16x8*)wbigpk, (const bf16x8*)wvocpk,
      bqk, bbig, bvoc, (float*)d_out);
}